// Round 2
// baseline (761.896 us; speedup 1.0000x reference)
//
#include <hip/hip_runtime.h>
#include <hip/hip_bf16.h>

// DenseBlockEnd: out = relu(mask * (node + b1*sum_l A_l@Win_l + b2*BO@Wout))
// B=512, M=256, F=256, L_IN=2, L_OUT=1.
// Fused as C[131072,256] = X[131072,768] @ Wt^T + node, row-masked ReLU.
// Wt (bf16, beta-folded, [n][k] layout) staged in d_ws by prep kernel.
//
// R2 structure: NO LDS, NO barriers. Each wave computes a 64x64 output tile
// with A (fp32, cvt->bf16 in regs) and B (bf16 Wt, L2-resident) fragments
// loaded DIRECTLY global->register in MFMA layout. Waves fully independent;
// latency hidden by 12 in-flight loads per s-step x ~12 waves/CU.
// Block = 256 thr (4 waves) owning 64 rows x 256 cols; grid 2048.

#define BATCH  512
#define MAXA   256
#define FDIM   256
#define KTOT   768
#define TILE_M 64
#define NTILES 2048       // 131072 / 64

typedef __attribute__((ext_vector_type(8))) short  short8;   // 8 bf16 (MFMA A/B frag)
typedef __attribute__((ext_vector_type(4))) float  fx4;      // MFMA C/D frag

__device__ __forceinline__ unsigned short f2bf(float x) {
  // round-to-nearest-even fp32 -> bf16 (inputs are finite normals)
  unsigned int u = __builtin_bit_cast(unsigned int, x);
  u += 0x7fffu + ((u >> 16) & 1u);
  return (unsigned short)(u >> 16);
}

__device__ __forceinline__ short8 cvt8(fx4 a, fx4 b) {
  short8 r;
  r[0] = (short)f2bf(a[0]); r[1] = (short)f2bf(a[1]);
  r[2] = (short)f2bf(a[2]); r[3] = (short)f2bf(a[3]);
  r[4] = (short)f2bf(b[0]); r[5] = (short)f2bf(b[1]);
  r[6] = (short)f2bf(b[2]); r[7] = (short)f2bf(b[3]);
  return r;
}

// Wt[n*768 + k] = bf16(beta * W[k][n]); k<512 -> W_in (beta1), else W_out (beta2).
__global__ void prep_weights(const float* __restrict__ Win,
                             const float* __restrict__ Wout,
                             const float* __restrict__ b1,
                             const float* __restrict__ b2,
                             unsigned short* __restrict__ Wt) {
  int id = blockIdx.x * 256 + threadIdx.x;   // 0 .. 196607, id = n*768 + k
  int n = id / KTOT;
  int k = id - n * KTOT;
  float beta, w;
  if (k < 512) { beta = b1[0]; w = Win[k * FDIM + n]; }
  else         { beta = b2[0]; w = Wout[(k - 512) * FDIM + n]; }
  Wt[id] = f2bf(beta * w);
}

__launch_bounds__(256, 3)
__global__ void fused_main(const float* __restrict__ node,
                           const float* __restrict__ acts,   // [2][131072][256]
                           const float* __restrict__ bouts,  // [1][131072][256]
                           const int*   __restrict__ mol_slice,
                           const unsigned short* __restrict__ Wt,
                           float* __restrict__ out) {
  const int tile  = blockIdx.x;        // 2048 tiles of 64 rows
  const int bmol  = tile >> 2;
  const int m0    = (tile & 3) << 6;
  const int slice = mol_slice[bmol];
  const int t     = threadIdx.x;
  const long rowBase = (long)tile * TILE_M;

  if (slice <= m0) {
    // whole tile masked: zero-fill 64x256 output, skip all reads/compute
    fx4 z = {0.f, 0.f, 0.f, 0.f};
    fx4* o4 = (fx4*)(out + rowBase * FDIM);
#pragma unroll
    for (int i = 0; i < 16; ++i) o4[i * 256 + t] = z;
    return;
  }

  const int lane = t & 63;
  const int wv   = t >> 6;            // 4 waves, each 64 rows x 64 cols
  const int wn   = wv << 6;           // wave col offset: 0/64/128/192
  const int r15  = lane & 15;
  const int kl   = (lane >> 4) << 3;  // k sub-offset within frag: 0/8/16/24

  fx4 acc[4][4];
#pragma unroll
  for (int i = 0; i < 4; ++i)
#pragma unroll
    for (int j = 0; j < 4; ++j) acc[i][j] = (fx4){0.f, 0.f, 0.f, 0.f};

  // per-frag global bases (MFMA-layout direct loads)
  long aoff[4];                        // fp32 element offsets into src
#pragma unroll
  for (int i = 0; i < 4; ++i)
    aoff[i] = (rowBase + (i << 4) + r15) * (long)FDIM + kl;
  const unsigned short* wb[4];         // bf16 pointers into Wt
#pragma unroll
  for (int j = 0; j < 4; ++j)
    wb[j] = Wt + (wn + (j << 4) + r15) * KTOT + kl;

  const float* acts2 = acts + 33554432;

#pragma unroll
  for (int seg = 0; seg < 3; ++seg) {
    const float* src = (seg == 0) ? acts : ((seg == 1) ? acts2 : bouts);
    const int segk = seg << 8;         // global k base of this segment
    for (int t4 = 0; t4 < 4; ++t4) {
      const int k0 = t4 << 6;          // k within segment: 0/64/128/192
#pragma unroll
      for (int s = 0; s < 2; ++s) {
        const int ks = k0 + (s << 5);  // 32-wide MFMA k-slice
        // B frags: 4 x 16B from L2-resident Wt
        short8 bfr[4];
#pragma unroll
        for (int j = 0; j < 4; ++j)
          bfr[j] = *(const short8*)(wb[j] + segk + ks);
        // A frags: 8 fp32 each, batched loads then cvt
        fx4 u0[4], u1[4];
#pragma unroll
        for (int i = 0; i < 4; ++i) {
          const float* p = src + aoff[i] + ks;
          u0[i] = *(const fx4*)p;
          u1[i] = *(const fx4*)(p + 4);
        }
        short8 af[4];
#pragma unroll
        for (int i = 0; i < 4; ++i) af[i] = cvt8(u0[i], u1[i]);
#pragma unroll
        for (int i = 0; i < 4; ++i)
#pragma unroll
          for (int j = 0; j < 4; ++j)
            acc[i][j] = __builtin_amdgcn_mfma_f32_16x16x32_bf16(af[i], bfr[j], acc[i][j], 0, 0, 0);
      }
    }
  }

  // epilogue: C/D layout col=lane&15, row=(lane>>4)*4+reg (m89-verified)
  const int cq = lane >> 4;
  const int cl = lane & 15;
#pragma unroll
  for (int i = 0; i < 4; ++i) {
    const int rb = (i << 4) + (cq << 2);
#pragma unroll
    for (int r = 0; r < 4; ++r) {
      const int lrow = rb + r;
      const int m = m0 + lrow;
      const long gro = (rowBase + lrow) * FDIM;
      const bool act = m < slice;
#pragma unroll
      for (int j = 0; j < 4; ++j) {
        const int col = wn + (j << 4) + cl;
        float v = 0.f;
        if (act) {
          v = node[gro + col] + acc[i][j][r];
          v = fmaxf(v, 0.f);
        }
        out[gro + col] = v;
      }
    }
  }
}

extern "C" void kernel_launch(void* const* d_in, const int* in_sizes, int n_in,
                              void* d_out, int out_size, void* d_ws, size_t ws_size,
                              hipStream_t stream) {
  const float* node  = (const float*)d_in[0];
  const float* acts  = (const float*)d_in[1];
  const float* bouts = (const float*)d_in[2];
  const int*   mslc  = (const int*)d_in[3];
  const float* Win   = (const float*)d_in[4];
  const float* Wout  = (const float*)d_in[5];
  const float* b1    = (const float*)d_in[6];
  const float* b2    = (const float*)d_in[7];
  float* out = (float*)d_out;
  unsigned short* Wt = (unsigned short*)d_ws;   // 768*256*2 = 393216 B

  prep_weights<<<dim3(768), dim3(256), 0, stream>>>(Win, Wout, b1, b2, Wt);
  fused_main<<<dim3(NTILES), dim3(256), 0, stream>>>(node, acts, bouts, mslc, Wt, out);
}